// Round 11
// baseline (8476.296 us; speedup 1.0000x reference)
//
#include <hip/hip_runtime.h>
#include <stdint.h>

// SpikingNetwork B=128 T=128 I=1024 dims 2048/2048/1024, beta=0.9, thr=1.0.
// R15: occupancy via MORE THREADS (R14's error: halved LDS but kept 256 blocks
// — occupancy is total-thread-bound, not packing-bound). 512 blocks x 512 thr
// = 16 waves/CU (2x R11), 2 blocks/CU (LDS ~70KB). Each block computes ONE
// 512-k part of a 64m x 64n tile, 4m x 2n per thread (4096 FMA/thr/t):
// L0 = 64 tiles x ksplit2 (128 blk), L1 = 64 x 4 (256), L2 = 32 x 4 (128).
// All merges cross-block via R5/R11's proven single-buffered global partials
// + tid0-spun flags; owner folds ((P0+P1)+P2)+P3 ascending. DAG bit-identical
// to R5..R14: 512-k ascending fmac chains, __fadd_rn merges in order, LIF
// rounding verbatim. Register-prefetch stays abandoned (5/5 spilled).
// launch_bounds(512,4) -> VGPR cap 128 (R14 measured 64 at this tile shape).

#define TT   128
#define NB   128
#define DD2  1024

// ws layout (u32 units) — R4's proven 14,160,896 B budget
#define SPK0_OFF 0u
#define SPK1_OFF (128u*128u*64u)                 // 1,048,576
#define PART_OFF (2u*128u*128u*64u)              // 2,097,152
#define NHELP    352u                            // slots x 4096 floats (16KB)
#define FLG_OFF  (PART_OFF + NHELP*4096u)        // 3,538,944
#define NFLG     1280u                           // pflag352 oflag192 done0 256 done1 256 (1056 used)
#define WS_NEED_BYTES ((size_t)(FLG_OFF + NFLG) * 4u)   // 14,160,896

__device__ __forceinline__ void wait_ge(uint32_t* p, uint32_t tgt){
  while (__hip_atomic_load(p, __ATOMIC_ACQUIRE, __HIP_MEMORY_SCOPE_AGENT) < tgt)
    __builtin_amdgcn_s_sleep(1);
}

// LDS column swizzle for lA: 4-float granules (b128-aligned); constant over a
// 4-aligned k-granule. Spreads staging stores and fma reads across banks.
__device__ __forceinline__ constexpr int fswz(int k){
  return (k & 16) | ((k ^ (k >> 3)) & 12);
}

__global__ void sentinel_kernel(float* o){ o[0] = 42.0f; }   // ws-too-small marker

__global__ __launch_bounds__(512, 4) void snn_kernel(
    const float* __restrict__ x,
    const float* __restrict__ W0, const float* __restrict__ b0,
    const float* __restrict__ W1, const float* __restrict__ b1,
    const float* __restrict__ W2, const float* __restrict__ b2,
    float* __restrict__ out, uint32_t* __restrict__ ws)
{
  __shared__ __align__(16) float lA[128][68];   // [k][m^swz], 34,816 B
  __shared__ __align__(16) float lB[64][132];   // [n][k],     33,792 B
  __shared__ uint32_t lBits[128];               // 64 rows x 2 words
  // total ~69.6 KB -> exactly 2 blocks/CU; 512 blocks all co-resident

  const int tid = threadIdx.x;
  const int tm  = tid & 15;      // m-group: rows tm*4 .. +3
  const int tn  = tid >> 4;      // n-group: cols tn*2 .. +1  (0..31)
  const int bid = blockIdx.x;

  uint32_t* spikes0  = ws + SPK0_OFF;
  uint32_t* spikes1  = ws + SPK1_OFF;
  float*    partials = (float*)(ws + PART_OFF);   // [NHELP][4096]
  uint32_t* flg   = ws + FLG_OFF;
  uint32_t* pflag = flg;            // [352] helper(hslot)->owner: partial t ready
  uint32_t* oflag = flg + 352;      // [192] owner(ownerid)->helpers: consumed t
  uint32_t* done0 = flg + 544;      // [2][128] per m-strip, target 32
  uint32_t* done1 = flg + 800;      // [2][128] per m-strip, target 32

  int group, pairk, tl, m0, n0, K, ksp, hslot, ownerid;
  const float *Wl, *bl;
  const uint32_t* spkIn; uint32_t* spkOut;
  uint32_t *dIn, *dOut;
  if (bid < 128) {          // L0: 64 tiles 64x64, K=1024, ksplit2
    group=0; ksp=2; pairk=bid&1; tl=bid>>1;
    m0=(tl>>5)*64; n0=(tl&31)*64; K=1024; Wl=W0; bl=b0;
    spkIn=nullptr; spkOut=spikes0;
    dIn=nullptr; dOut=done0+(m0>>6)*128;
    hslot = tl; ownerid = tl;
  } else if (bid < 384) {   // L1: 64 tiles 64x64, K=2048, ksplit4
    group=1; ksp=4; int rel=bid-128; pairk=rel&3; tl=rel>>2;
    m0=(tl>>5)*64; n0=(tl&31)*64; K=2048; Wl=W1; bl=b1;
    spkIn=spikes0; spkOut=spikes1;
    dIn=done0+(m0>>6)*128; dOut=done1+(m0>>6)*128;
    hslot = 64 + tl*3 + (pairk-1); ownerid = 64 + tl;
  } else {                  // L2: 32 tiles 64x64, K=2048, ksplit4
    group=2; ksp=4; int rel=bid-384; pairk=rel&3; tl=rel>>2;
    m0=(tl>>4)*64; n0=(tl&15)*64; K=2048; Wl=W2; bl=b2;
    spkIn=spikes1; spkOut=nullptr;
    dIn=done1+(m0>>6)*128; dOut=nullptr;
    hslot = 256 + tl*3 + (pairk-1); ownerid = 128 + tl;
  }
  const bool owner = (pairk == 0);
  const int  K0    = pairk * 512;

  const float bias0 = bl[n0 + tn*2 + 0];
  const float bias1 = bl[n0 + tn*2 + 1];

  float vst[4][2];   // membrane potential (owner blocks)
  #pragma unroll
  for (int r = 0; r < 4; ++r) { vst[r][0] = 0.f; vst[r][1] = 0.f; }

  // staging decomposition: idx = tid + it*512 -> row idx>>5 (0..63), kq idx&31
  // spike expansion: 4 rows x 4 k per thread
  const int e_q  = tid & 15;        // row quad e_q*4 .. +3
  const int e_g  = tid >> 4;        // k-granule 0..31 (4 k each)
  const int e_w  = e_g >> 3;        // which 32-bit word (128k = 4 words)
  const int e_sh = (e_g & 7) * 4;   // bit base within word

  for (int t = 0; t < TT; ++t) {
    if (dIn) {  // previous layer's spikes for this m-strip must be complete
      if (tid == 0) wait_ge(&dIn[t], 32u);
      __syncthreads();
    }

    float acc[4][2];   // ONE 512-k chain
    #pragma unroll
    for (int r = 0; r < 4; ++r) { acc[r][0] = 0.f; acc[r][1] = 0.f; }

    #pragma unroll 1
    for (int ch = 0; ch < 4; ++ch) {            // 4 chunks of 128 k
      const int kb = K0 + ch*128;

      // ---- stage B: weights, natural [n][k] (64 rows x 128 k, 4 f4/thread)
      #pragma unroll
      for (int it = 0; it < 4; ++it) {
        int idx = tid + it*512;
        int nrow = idx >> 5, kq = idx & 31;
        float4 w = *(const float4*)(Wl + (size_t)(n0+nrow)*K + kb + kq*4);
        *(float4*)&lB[nrow][kq*4] = w;
      }

      // ---- stage A
      if (group == 0) {       // x[b,t,k] -> lA[k][m^swz]
        #pragma unroll
        for (int it = 0; it < 4; ++it) {
          int idx = tid + it*512;
          int mrow = idx >> 5, kq = idx & 31;
          float4 v = *(const float4*)(x + ((size_t)(m0+mrow)*TT + t)*1024 + kb + kq*4);
          int k0 = kq*4;
          const int sw = fswz(k0);
          const int col = mrow ^ sw;
          lA[k0+0][col] = v.x; lA[k0+1][col] = v.y;
          lA[k0+2][col] = v.z; lA[k0+3][col] = v.w;
        }
      } else {                // spike bits -> {0,1} f32; 4 rows x 4 k per thread
        const size_t rbase = ((size_t)t*NB + m0 + e_q*4)*64 + (kb>>5) + e_w;
        uint32_t w0 = __hip_atomic_load(&spkIn[rbase      ], __ATOMIC_RELAXED, __HIP_MEMORY_SCOPE_AGENT);
        uint32_t w1 = __hip_atomic_load(&spkIn[rbase +  64], __ATOMIC_RELAXED, __HIP_MEMORY_SCOPE_AGENT);
        uint32_t w2 = __hip_atomic_load(&spkIn[rbase + 128], __ATOMIC_RELAXED, __HIP_MEMORY_SCOPE_AGENT);
        uint32_t w3 = __hip_atomic_load(&spkIn[rbase + 192], __ATOMIC_RELAXED, __HIP_MEMORY_SCOPE_AGENT);
        #pragma unroll
        for (int j = 0; j < 4; ++j) {
          const int k  = e_g*4 + j;          // local 0..127
          const int sh = e_sh + j;
          float4 f;
          f.x = ((w0 >> sh) & 1u) ? 1.0f : 0.0f;
          f.y = ((w1 >> sh) & 1u) ? 1.0f : 0.0f;
          f.z = ((w2 >> sh) & 1u) ? 1.0f : 0.0f;
          f.w = ((w3 >> sh) & 1u) ? 1.0f : 0.0f;
          *(float4*)&lA[k][(e_q*4) ^ fswz(k)] = f;
        }
      }
      __syncthreads();

      // ---- FMA micro-kernel: 128 k x (4m x 2n), sequential ascending k
      #pragma unroll 4
      for (int k4 = 0; k4 < 32; ++k4) {
        const int kbase = k4*4;
        const int sw = fswz(kbase);           // constant over the 4 sub-ks
        const float* pa = &lA[kbase][(tm*4) ^ sw];
        const float4 q0 = *(const float4*)&lB[tn*2    ][kbase];
        const float4 q1 = *(const float4*)&lB[tn*2 + 1][kbase];
        #pragma unroll
        for (int u = 0; u < 4; ++u) {
          const float4 a  = *(const float4*)(pa + u*68);
          const float b0v = (u==0) ? q0.x : (u==1) ? q0.y : (u==2) ? q0.z : q0.w;
          const float b1v = (u==0) ? q1.x : (u==1) ? q1.y : (u==2) ? q1.z : q1.w;
          acc[0][0] = __builtin_fmaf(a.x, b0v, acc[0][0]);
          acc[1][0] = __builtin_fmaf(a.y, b0v, acc[1][0]);
          acc[2][0] = __builtin_fmaf(a.z, b0v, acc[2][0]);
          acc[3][0] = __builtin_fmaf(a.w, b0v, acc[3][0]);
          acc[0][1] = __builtin_fmaf(a.x, b1v, acc[0][1]);
          acc[1][1] = __builtin_fmaf(a.y, b1v, acc[1][1]);
          acc[2][1] = __builtin_fmaf(a.z, b1v, acc[2][1]);
          acc[3][1] = __builtin_fmaf(a.w, b1v, acc[3][1]);
        }
      }
      __syncthreads();
    }

    if (!owner) {
      // ship P_pairk; single-buffered vs owner's consumption of t-1
      if (t >= 1) { if (tid == 0) wait_ge(&oflag[ownerid], (uint32_t)t); __syncthreads(); }
      uint64_t* pb = (uint64_t*)(partials + (size_t)hslot*4096) + tid*4;
      #pragma unroll
      for (int r = 0; r < 4; ++r) {
        union { float f[2]; uint64_t u; } cv;
        cv.f[0] = acc[r][0]; cv.f[1] = acc[r][1];
        __hip_atomic_store(&pb[r], cv.u, __ATOMIC_RELAXED, __HIP_MEMORY_SCOPE_AGENT);
      }
      __syncthreads();
      if (tid == 0) __hip_atomic_store(&pflag[hslot], (uint32_t)(t+1), __ATOMIC_RELEASE, __HIP_MEMORY_SCOPE_AGENT);
      continue;
    }

    // ---- owner: fold P1 (, P2, P3) in ascending-k order (__fadd_rn)
    {
      if (tid == 0)
        for (int p = 1; p < ksp; ++p) {
          int hs = (group==0) ? tl : ((group==1) ? (64 + tl*3 + (p-1)) : (256 + tl*3 + (p-1)));
          wait_ge(&pflag[hs], (uint32_t)(t+1));
        }
      __syncthreads();
      for (int p = 1; p < ksp; ++p) {
        int hs = (group==0) ? tl : ((group==1) ? (64 + tl*3 + (p-1)) : (256 + tl*3 + (p-1)));
        uint64_t* pb = (uint64_t*)(partials + (size_t)hs*4096) + tid*4;
        #pragma unroll
        for (int r = 0; r < 4; ++r) {
          union { uint64_t u; float f[2]; } cv;
          cv.u = __hip_atomic_load(&pb[r], __ATOMIC_RELAXED, __HIP_MEMORY_SCOPE_AGENT);
          acc[r][0] = __fadd_rn(acc[r][0], cv.f[0]);
          acc[r][1] = __fadd_rn(acc[r][1], cv.f[1]);
        }
      }
      __syncthreads();
      if (tid == 0) __hip_atomic_store(&oflag[ownerid], (uint32_t)(t+1), __ATOMIC_RELEASE, __HIP_MEMORY_SCOPE_AGENT);
    }

    if (group < 2) { if (tid < 128) lBits[tid] = 0; __syncthreads(); }

    // LIF: cur = acc + b (rn); v = 0.9*v + cur (mul+add rn, NO fma contraction);
    // spk = v > 1.0 strictly; v -= spk.
    float sv[4][2], vv8[4][2];
    #pragma unroll
    for (int r = 0; r < 4; ++r) {
      uint32_t msk = 0;
      #pragma unroll
      for (int c = 0; c < 2; ++c) {
        float cur = __fadd_rn(acc[r][c], c ? bias1 : bias0);
        float vv  = __fadd_rn(__fmul_rn(0.9f, vst[r][c]), cur);
        float s   = (vv > 1.0f) ? 1.0f : 0.0f;
        vv = __fsub_rn(vv, s);
        vst[r][c] = vv;
        sv[r][c] = s; vv8[r][c] = vv;
        msk |= (s != 0.f) ? (1u << ((tn*2 + c) & 31)) : 0u;
      }
      if (group < 2 && msk) atomicOr(&lBits[(tm*4 + r)*2 + (tn>>4)], msk);
    }

    if (group == 2) {
      #pragma unroll
      for (int r = 0; r < 4; ++r) {
        size_t o  = ((size_t)(m0 + tm*4 + r)*TT + t)*DD2 + n0 + tn*2;
        *(float2*)(out + o)  = make_float2(sv[r][0], sv[r][1]);
        size_t ov = (size_t)NB*TT*DD2 + o;
        *(float2*)(out + ov) = make_float2(vv8[r][0], vv8[r][1]);
      }
    } else {
      __syncthreads();
      if (tid < 128)
        __hip_atomic_store(&spkOut[((size_t)t*NB + m0 + (tid>>1))*64 + (n0>>5) + (tid&1)],
                           lBits[tid], __ATOMIC_RELAXED, __HIP_MEMORY_SCOPE_AGENT);
      __syncthreads();
      if (tid == 0) __hip_atomic_fetch_add(&dOut[t], 1u, __ATOMIC_RELEASE, __HIP_MEMORY_SCOPE_AGENT);
    }
  }
}

extern "C" void kernel_launch(void* const* d_in, const int* in_sizes, int n_in,
                              void* d_out, int out_size, void* d_ws, size_t ws_size,
                              hipStream_t stream) {
  (void)in_sizes; (void)n_in; (void)out_size;
  float* outf = (float*)d_out;
  if (ws_size < WS_NEED_BYTES) {            // diagnostic: absmax ~41 => ws too small
    sentinel_kernel<<<1, 1, 0, stream>>>(outf);
    return;
  }
  const float* x  = (const float*)d_in[0];
  const float* W0 = (const float*)d_in[1];
  const float* b0 = (const float*)d_in[2];
  const float* W1 = (const float*)d_in[3];
  const float* b1 = (const float*)d_in[4];
  const float* W2 = (const float*)d_in[5];
  const float* b2 = (const float*)d_in[6];
  uint32_t* ws = (uint32_t*)d_ws;

  // zero flags (spikes/partials are write-before-read; flags gate everything)
  hipMemsetAsync(ws + FLG_OFF, 0, NFLG * sizeof(uint32_t), stream);

  snn_kernel<<<512, 512, 0, stream>>>(x, W0, b0, W1, b1, W2, b2, outf, ws);
}